// Round 7
// baseline (95.467 us; speedup 1.0000x reference)
//
#include <hip/hip_runtime.h>

#define NB    256
#define DIN   128
#define HH    512
#define RANK  8
#define SCALE 2.0f
#define LN2   0.69314718f
#define C192  5.2083335e-3f

// ---- workspace layout (float offsets) ----
#define WS_ACC   0          // [2816 rows][512 h] fp32  (rows: v*256+s for v=0..8, then Q2 2304+s, Q4 2560+s)
#define WS_B16   1441792    // fp16 [2 layer][2304 rows][512 k]   (rows: v*256+s)
#define WS_W16   2621440    // fp16 [2 layer][3 mat][512][512]    (mat: W, W^2, W^4)
#define WS_XPRE  3407872    // fp32 [2 layer][256 s][512 h]
#define WS_SCAL  3670016    // fp32 [2 layer][256 s][80] (0=Z0, 1..8=u_r, 16..79=M[r*8+s])
#define WS_END   3710976

typedef float v2f __attribute__((ext_vector_type(2)));
typedef _Float16 f16x8 __attribute__((ext_vector_type(8)));
typedef float f32x4 __attribute__((ext_vector_type(4)));

__device__ __forceinline__ v2f mk2(float a, float b) { v2f r; r.x = a; r.y = b; return r; }

// ---- packed fp32 VOP3P helpers (fallback kernel) ----
__device__ __forceinline__ v2f pk_fma(v2f a, v2f b, v2f c) {
    v2f d; asm("v_pk_fma_f32 %0, %1, %2, %3" : "=v"(d) : "v"(a), "v"(b), "v"(c)); return d;
}
__device__ __forceinline__ v2f pk_mul(v2f a, v2f b) {
    v2f d; asm("v_pk_mul_f32 %0, %1, %2" : "=v"(d) : "v"(a), "v"(b)); return d;
}
__device__ __forceinline__ v2f pk_fma_blo(v2f a, v2f b, v2f c) {
    v2f d; asm("v_pk_fma_f32 %0, %1, %2, %3 op_sel:[0,0,0] op_sel_hi:[1,0,1]"
               : "=v"(d) : "v"(a), "v"(b), "v"(c)); return d;
}
__device__ __forceinline__ v2f pk_fma_bhi(v2f a, v2f b, v2f c) {
    v2f d; asm("v_pk_fma_f32 %0, %1, %2, %3 op_sel:[0,1,0] op_sel_hi:[1,1,1]"
               : "=v"(d) : "v"(a), "v"(b), "v"(c)); return d;
}

__device__ __forceinline__ float sp_stable(float v) {
    float e = __expf(-fabsf(v));
    return fmaxf(v, 0.0f) + __logf(1.0f + e);
}
__device__ __forceinline__ float sp_poly(float v) {
    float u = v * v;
    float t = fmaf(u, -C192, 0.125f);
    t = fmaf(u, t, LN2);
    return fmaf(v, 0.5f, t);
}

#define DPP_ADD(x, ctrl, rm, bm, bc)                                            \
    (x) = (x) + __int_as_float(__builtin_amdgcn_update_dpp(                     \
              0, __float_as_int(x), (ctrl), (rm), (bm), (bc)))

__device__ __forceinline__ float wave_sum64(float x) {
    DPP_ADD(x, 0x111, 0xf, 0xf, true);
    DPP_ADD(x, 0x112, 0xf, 0xf, true);
    DPP_ADD(x, 0x114, 0xf, 0xf, true);
    DPP_ADD(x, 0x118, 0xf, 0xf, true);
    DPP_ADD(x, 0x142, 0xa, 0xf, false);
    DPP_ADD(x, 0x143, 0xc, 0xf, false);
    return x;
}

// ------------------------------------------------------------------
// Shared: build B rows (c at row s; y_r = c*az_r at row (1+r)*256+s) in fp16
// and scalars (Z0, u_r, M_rs) for layer `ell`. Call from all 1024 threads.
// ------------------------------------------------------------------
__device__ void build_b_scal(int b, int ell, const float* __restrict__ Az,
                             float* __restrict__ ws, const float* __restrict__ z_s,
                             float* __restrict__ y_s, float* __restrict__ az_s,
                             float* __restrict__ wred)
{
    const int tid = threadIdx.x;
    _Float16* wsB = (_Float16*)(ws + WS_B16) + (size_t)ell * (2304 * 512);
    float* wsS = ws + WS_SCAL + (ell * 256 + b) * 80;
    __syncthreads();   // z_s ready
    if (tid < 512) {
        const int k = tid, w = tid >> 6;
        float c = z_s[k];
        wsB[(size_t)b * 512 + k] = (_Float16)c;
        float ys[RANK];
        #pragma unroll
        for (int r = 0; r < RANK; ++r) {
            float az = Az[((size_t)b * RANK + r) * HH + k];
            az_s[r * HH + k] = az;
            float y = c * az;
            y_s[r * HH + k] = y;
            wsB[(size_t)((1 + r) * 256 + b) * 512 + k] = (_Float16)y;
            ys[r] = y;
        }
        float zp = wave_sum64(c);
        if ((tid & 63) == 63) wred[w * 12 + 0] = zp;
        #pragma unroll
        for (int r = 0; r < RANK; ++r) {
            float up = wave_sum64(ys[r]);
            if ((tid & 63) == 63) wred[w * 12 + 1 + r] = up;
        }
    }
    __syncthreads();
    if (tid < 9) {
        float s = 0.f;
        #pragma unroll
        for (int w = 0; w < 8; ++w) s += wred[w * 12 + tid];
        wsS[tid] = s;
    }
    if (tid < 512) {
        const int p = tid >> 3, li = tid & 7;
        const int r = p >> 3, s2 = p & 7;
        float m = 0.f;
        #pragma unroll 8
        for (int j = 0; j < 64; ++j) {
            int k = li + 8 * j;
            m += y_s[r * HH + k] * az_s[s2 * HH + k];
        }
        m += __shfl_down(m, 4, 8);
        m += __shfl_down(m, 2, 8);
        m += __shfl_down(m, 1, 8);
        if (li == 0) wsS[16 + p] = m;
    }
}

// ------------------------------------------------------------------
// kprep: W->fp16 {W,W^2,W^4} for both layers; per-sample tx, xpre0/1/2,
// z0, B1 rows + layer-1 scalars.
// ------------------------------------------------------------------
__global__ __launch_bounds__(1024, 4) void kprep(
    const float* __restrict__ x,
    const float* __restrict__ Wx0, const float* __restrict__ b0,
    const float* __restrict__ Ax0, const float* __restrict__ Bx0, const float* __restrict__ bd0,
    const float* __restrict__ Wx1, const float* __restrict__ b1,
    const float* __restrict__ Ax1, const float* __restrict__ Bx1, const float* __restrict__ bd1,
    const float* __restrict__ Wx2, const float* __restrict__ b2,
    const float* __restrict__ Ax2, const float* __restrict__ Bx2, const float* __restrict__ bd2,
    const float* __restrict__ Az1, const float* __restrict__ Wz1,
    const float* __restrict__ Wz2, float* __restrict__ ws)
{
    const int b = blockIdx.x, tid = threadIdx.x;
    __shared__ float x_s[DIN];
    __shared__ float tx_s[3][RANK];
    __shared__ float xpre0_s[HH];
    __shared__ float z_s[HH];
    __shared__ float y_s[RANK * HH];
    __shared__ float az_s[RANK * HH];
    __shared__ float wred[96];

    // ---- W -> fp16 {W, W^2, W^4}, both layers (independent of sample phases) ----
    {
        _Float16* W16 = (_Float16*)(ws + WS_W16);
        #pragma unroll
        for (int j = 0; j < 2; ++j) {
            const int e = b * 2048 + tid + j * 1024;   // 0 .. 524287
            const int l = e >> 18;                     // layer
            const int idx = e & 262143;
            float w = (l ? Wz2 : Wz1)[idx];
            float w2 = w * w;
            _Float16* wh = W16 + (size_t)l * 786432;
            wh[idx] = (_Float16)w;
            wh[262144 + idx] = (_Float16)w2;
            wh[524288 + idx] = (_Float16)(w2 * w2);
        }
    }

    if (tid < DIN) x_s[tid] = x[b * DIN + tid];
    __syncthreads();

    if (tid < 384) {
        const int g = tid >> 7, t = tid & 127;
        const int r = t >> 4, l = t & 15;
        const float* A  = (g == 0) ? Ax0 : (g == 1) ? Ax1 : Ax2;
        const float* Ab = A + ((size_t)b * RANK + r) * DIN;
        float s = 0.f;
        #pragma unroll
        for (int k = 0; k < 8; ++k) { int d = l + 16 * k; s += Ab[d] * x_s[d]; }
        s += __shfl_down(s, 8, 16);
        s += __shfl_down(s, 4, 16);
        s += __shfl_down(s, 2, 16);
        s += __shfl_down(s, 1, 16);
        if (l == 0) tx_s[g][r] = s;
    }
    __syncthreads();

    #pragma unroll 1
    for (int idx = tid; idx < 3 * HH; idx += 1024) {
        const int l = idx >> 9;
        const int h = idx & (HH - 1);
        const float* Wxl = (l == 0) ? Wx0 : (l == 1) ? Wx1 : Wx2;
        const float* bl  = (l == 0) ? b0  : (l == 1) ? b1  : b2;
        const float* Bxl = (l == 0) ? Bx0 : (l == 1) ? Bx1 : Bx2;
        const float* bdl = (l == 0) ? bd0 : (l == 1) ? bd1 : bd2;
        const float4* wrow = reinterpret_cast<const float4*>(Wxl + h * DIN);
        float s = 0.f;
        #pragma unroll 8
        for (int q = 0; q < DIN / 4; ++q) {
            float4 w = wrow[q];
            const float* xs = &x_s[q * 4];
            s += w.x * xs[0] + w.y * xs[1] + w.z * xs[2] + w.w * xs[3];
        }
        const float* bxr = Bxl + ((size_t)b * HH + h) * RANK;
        float t = 0.f;
        #pragma unroll
        for (int r = 0; r < RANK; ++r) t += bxr[r] * tx_s[l][r];
        float v = s + SCALE * t + bl[h] + bdl[(size_t)b * HH + h];
        if (l == 0) xpre0_s[h] = v;
        else        ws[WS_XPRE + ((l - 1) * 256 + b) * HH + h] = v;
    }
    __syncthreads();

    if (tid < 512) z_s[tid] = sp_stable(xpre0_s[tid]);
    build_b_scal(b, 0, Az1, ws, z_s, y_s, az_s, wred);
}

// ------------------------------------------------------------------
// kz: MFMA GEMM. One wave = one 16x16 C tile, K=512 via 16 mfma_16x16x32_f16.
//   n-tiles 0..143   : A = W    , B rows nt*16..       -> ACC rows (same)
//   n-tiles 144..159 : A = W^2  , B rows (nt-144)*16.. -> ACC rows 2304..2559
//   n-tiles 160..175 : A = W^4  , B rows (nt-160)*16.. -> ACC rows 2560..2815
// ------------------------------------------------------------------
__global__ __launch_bounds__(256, 8) void kz(
    const _Float16* __restrict__ W3, const _Float16* __restrict__ Bm,
    float* __restrict__ acco)
{
    const int gw   = blockIdx.x * 4 + (threadIdx.x >> 6);
    const int lane = threadIdx.x & 63;
    const int nt = gw >> 5;          // 0..175
    const int ht = gw & 31;          // 0..31
    const int sel = (nt < 144) ? 0 : ((nt < 160) ? 1 : 2);
    const int nb  = (sel == 0) ? nt : ((sel == 1) ? (nt - 144) : (nt - 160));

    const _Float16* A = W3 + (size_t)sel * 262144;
    const int m  = lane & 15;
    const int kd = (lane >> 4) * 8;
    const _Float16* ap = A  + (size_t)(ht * 16 + m) * 512 + kd;
    const _Float16* bp = Bm + (size_t)(nb * 16 + m) * 512 + kd;

    f32x4 acc = {0.f, 0.f, 0.f, 0.f};
    #pragma unroll
    for (int ks = 0; ks < 16; ++ks) {
        f16x8 a = *reinterpret_cast<const f16x8*>(ap + ks * 32);
        f16x8 bfr = *reinterpret_cast<const f16x8*>(bp + ks * 32);
        acc = __builtin_amdgcn_mfma_f32_16x16x32_f16(a, bfr, acc, 0, 0, 0);
    }
    const int accrow = nt * 16 + m;              // D col = lane&15 -> n
    const int h0 = ht * 16 + (lane >> 4) * 4;    // D row = (lane>>4)*4 + r -> h
    #pragma unroll
    for (int r = 0; r < 4; ++r)
        acco[(size_t)accrow * 512 + h0 + r] = acc[r];
}

// ------------------------------------------------------------------
// kmid: merge layer-1 ACC -> z1; build B2 rows + layer-2 scalars.
// ------------------------------------------------------------------
__global__ __launch_bounds__(1024, 4) void kmid(
    const float* __restrict__ Az2, const float* __restrict__ Bz1,
    float* __restrict__ ws)
{
    const int b = blockIdx.x, tid = threadIdx.x;
    __shared__ float z_s[HH];
    __shared__ float sc_s[80];
    __shared__ float y_s[RANK * HH];
    __shared__ float az_s[RANK * HH];
    __shared__ float wred[96];

    if (tid < 80) sc_s[tid] = ws[WS_SCAL + b * 80 + tid];
    __syncthreads();
    if (tid < 512) {
        const int h = tid;
        const float* acc = ws + WS_ACC;
        float P  = acc[(size_t)b * 512 + h];
        float Q2 = acc[(size_t)(2304 + b) * 512 + h];
        float Q4 = acc[(size_t)(2560 + b) * 512 + h];
        const float* bz = Bz1 + ((size_t)b * HH + h) * RANK;
        float uDot = 0.f, RDot = 0.f, quad = 0.f;
        #pragma unroll
        for (int r = 0; r < RANK; ++r) {
            float br = bz[r];
            uDot = fmaf(br, sc_s[1 + r], uDot);
            RDot = fmaf(br, acc[(size_t)((1 + r) * 256 + b) * 512 + h], RDot);
            float mr = 0.f;
            #pragma unroll
            for (int s = 0; s < RANK; ++s) mr = fmaf(sc_s[16 + r * 8 + s], bz[s], mr);
            quad = fmaf(br, mr, quad);
        }
        float pre = ws[WS_XPRE + (0 * 256 + b) * HH + h]
                  + LN2 * sc_s[0] + 0.5f * P + uDot
                  + 0.125f * Q2 + 0.5f * RDot + 0.5f * quad - Q4 * C192;
        z_s[h] = sp_stable(pre);
    }
    build_b_scal(b, 1, Az2, ws, z_s, y_s, az_s, wred);
}

// ------------------------------------------------------------------
// kout: merge layer-2 ACC -> z2; output layer; reduce to out[b].
// ------------------------------------------------------------------
__global__ __launch_bounds__(512, 2) void kout(
    const float* __restrict__ x,
    const float* __restrict__ oWx, const float* __restrict__ ob,
    const float* __restrict__ oAx, const float* __restrict__ oBx, const float* __restrict__ obd,
    const float* __restrict__ oWz, const float* __restrict__ oAz, const float* __restrict__ oBz,
    const float* __restrict__ Bz2, float* __restrict__ ws, float* __restrict__ out)
{
    const int b = blockIdx.x, tid = threadIdx.x;
    __shared__ float x_s[DIN];
    __shared__ float sc_s[80];
    __shared__ float red_s[HH];
    __shared__ float tx_s[RANK];

    if (tid < DIN) x_s[tid] = x[b * DIN + tid];
    if (tid < 80) sc_s[tid] = ws[WS_SCAL + (256 + b) * 80 + tid];
    __syncthreads();

    float partial;
    {
        const int h = tid;
        const float* acc = ws + WS_ACC;
        float P  = acc[(size_t)b * 512 + h];
        float Q2 = acc[(size_t)(2304 + b) * 512 + h];
        float Q4 = acc[(size_t)(2560 + b) * 512 + h];
        const float* bz = Bz2 + ((size_t)b * HH + h) * RANK;
        float uDot = 0.f, RDot = 0.f, quad = 0.f;
        #pragma unroll
        for (int r = 0; r < RANK; ++r) {
            float br = bz[r];
            uDot = fmaf(br, sc_s[1 + r], uDot);
            RDot = fmaf(br, acc[(size_t)((1 + r) * 256 + b) * 512 + h], RDot);
            float mr = 0.f;
            #pragma unroll
            for (int s = 0; s < RANK; ++s) mr = fmaf(sc_s[16 + r * 8 + s], bz[s], mr);
            quad = fmaf(br, mr, quad);
        }
        float pre = ws[WS_XPRE + (1 * 256 + b) * HH + h]
                  + LN2 * sc_s[0] + 0.5f * P + uDot
                  + 0.125f * Q2 + 0.5f * RDot + 0.5f * quad - Q4 * C192;
        float z2 = sp_stable(pre);
        float d = 0.f;
        #pragma unroll
        for (int r = 0; r < RANK; ++r)
            d = fmaf(oBz[b * RANK + r], oAz[((size_t)b * RANK + r) * HH + h], d);
        partial = z2 * sp_poly(fmaf(SCALE, d, oWz[h]));
        if (tid < DIN) partial += oWx[tid] * x_s[tid];
    }
    red_s[tid] = partial;
    __syncthreads();

    if (tid < 128) {
        const int r = tid >> 4, l = tid & 15;
        const float* Ab = oAx + ((size_t)b * RANK + r) * DIN;
        float s = 0.f;
        #pragma unroll
        for (int k = 0; k < 8; ++k) { int d = l + 16 * k; s += Ab[d] * x_s[d]; }
        s += __shfl_down(s, 8, 16);
        s += __shfl_down(s, 4, 16);
        s += __shfl_down(s, 2, 16);
        s += __shfl_down(s, 1, 16);
        if (l == 0) tx_s[r] = s;
    }
    __syncthreads();
    for (int st = 256; st > 0; st >>= 1) {
        if (tid < st) red_s[tid] += red_s[tid + st];
        __syncthreads();
    }
    if (tid == 0) {
        float t2 = 0.f;
        #pragma unroll
        for (int r = 0; r < RANK; ++r) t2 = fmaf(oBx[b * RANK + r], tx_s[r], t2);
        out[b] = red_s[0] + ob[0] + obd[b] + SCALE * t2;
    }
}

// ==================================================================
// Fallback single-kernel path (round-5 kernel) if ws too small.
// ==================================================================
__global__ __launch_bounds__(1024, 4) void lora_fused(
    const float* __restrict__ x,
    const float* __restrict__ Wx0, const float* __restrict__ b0,
    const float* __restrict__ Ax0, const float* __restrict__ Bx0, const float* __restrict__ bd0,
    const float* __restrict__ Wx1, const float* __restrict__ b1,
    const float* __restrict__ Ax1, const float* __restrict__ Bx1, const float* __restrict__ bd1,
    const float* __restrict__ Wx2, const float* __restrict__ b2,
    const float* __restrict__ Ax2, const float* __restrict__ Bx2, const float* __restrict__ bd2,
    const float* __restrict__ Wz1, const float* __restrict__ Az1, const float* __restrict__ Bz1,
    const float* __restrict__ Wz2, const float* __restrict__ Az2, const float* __restrict__ Bz2,
    const float* __restrict__ oWx, const float* __restrict__ ob,
    const float* __restrict__ oAx, const float* __restrict__ oBx, const float* __restrict__ obd,
    const float* __restrict__ oWz, const float* __restrict__ oAz, const float* __restrict__ oBz,
    float* __restrict__ out)
{
    const int b    = blockIdx.x;
    const int tid  = threadIdx.x;
    const int lane = tid & 63;
    const int wid  = tid >> 6;
    const int rg   = wid >> 1;
    const int ch   = wid & 1;
    const bool odd = lane & 1;

    __shared__ float x_s[DIN];
    __shared__ float z_s[HH];
    __shared__ float tx_s[4][RANK];
    __shared__ float xpre_s[3][HH];
    __shared__ float red4_s[4][2][HH + 2];
    __shared__ __attribute__((aligned(16))) float Az_s[2][RANK * HH];
    __shared__ __attribute__((aligned(16))) float Bz_s[2][HH * RANK];
    __shared__ float red8[16];

    const v2f cA2 = mk2(-C192, -C192);
    const v2f cB2 = mk2(0.125f, 0.125f);
    const v2f cL2 = mk2(LN2, LN2);
    const v2f cH2 = mk2(0.5f, 0.5f);

    if (tid < DIN) x_s[tid] = x[b * DIN + tid];
    {
        const float4* a1 = reinterpret_cast<const float4*>(Az1 + b * RANK * HH);
        const float4* a2 = reinterpret_cast<const float4*>(Az2 + b * RANK * HH);
        const float4* z1 = reinterpret_cast<const float4*>(Bz1 + b * HH * RANK);
        const float4* z2 = reinterpret_cast<const float4*>(Bz2 + b * HH * RANK);
        reinterpret_cast<float4*>(Az_s[0])[tid] = a1[tid];
        reinterpret_cast<float4*>(Az_s[1])[tid] = a2[tid];
        reinterpret_cast<float4*>(Bz_s[0])[tid] = z1[tid];
        reinterpret_cast<float4*>(Bz_s[1])[tid] = z2[tid];
    }
    __syncthreads();

    if (tid < 512) {
        const int g = tid >> 7;
        const int t = tid & 127;
        const int r = t >> 4, l = t & 15;
        const float* A  = (g == 0) ? Ax0 : (g == 1) ? Ax1 : (g == 2) ? Ax2 : oAx;
        const float* Ab = A + (b * RANK + r) * DIN;
        float s = 0.f;
        #pragma unroll
        for (int k = 0; k < 8; ++k) { int d = l + 16 * k; s += Ab[d] * x_s[d]; }
        s += __shfl_down(s, 8, 16);
        s += __shfl_down(s, 4, 16);
        s += __shfl_down(s, 2, 16);
        s += __shfl_down(s, 1, 16);
        if (l == 0) tx_s[g][r] = s;
    }
    __syncthreads();

    #pragma unroll 1
    for (int idx = tid; idx < 3 * HH; idx += 1024) {
        const int l = idx >> 9;
        const int h = idx & (HH - 1);
        const float* Wxl = (l == 0) ? Wx0 : (l == 1) ? Wx1 : Wx2;
        const float* bl  = (l == 0) ? b0  : (l == 1) ? b1  : b2;
        const float* Bxl = (l == 0) ? Bx0 : (l == 1) ? Bx1 : Bx2;
        const float* bdl = (l == 0) ? bd0 : (l == 1) ? bd1 : bd2;
        const float4* wrow = reinterpret_cast<const float4*>(Wxl + h * DIN);
        float s = 0.f;
        #pragma unroll 8
        for (int q = 0; q < DIN / 4; ++q) {
            float4 w = wrow[q];
            const float* xs = &x_s[q * 4];
            s += w.x * xs[0] + w.y * xs[1] + w.z * xs[2] + w.w * xs[3];
        }
        const float* bxr = Bxl + (b * HH + h) * RANK;
        float t = 0.f;
        #pragma unroll
        for (int r = 0; r < RANK; ++r) t += bxr[r] * tx_s[l][r];
        xpre_s[l][h] = s + SCALE * t + bl[h] + bdl[b * HH + h];
    }
    __syncthreads();

    if (tid < HH) z_s[tid] = sp_stable(xpre_s[0][tid]);
    __syncthreads();

    auto zlayer = [&](const float* __restrict__ Wz, int li) {
        const int c0 = ch * 256 + (lane << 2);
        v2f zk2[2], az[RANK][2];
        {
            float4 zz = *reinterpret_cast<const float4*>(&z_s[c0]);
            zk2[0] = mk2(zz.x, zz.y); zk2[1] = mk2(zz.z, zz.w);
        }
        #pragma unroll
        for (int r = 0; r < RANK; ++r) {
            float4 a4 = *reinterpret_cast<const float4*>(&Az_s[li][r * HH + c0]);
            az[r][0] = mk2(SCALE * a4.x, SCALE * a4.y);
            az[r][1] = mk2(SCALE * a4.z, SCALE * a4.w);
        }
        const float* wp = Wz + (rg * 64) * HH + c0;
        const float* bp = &Bz_s[li][(rg * 64) * RANK];
        float* rp = &red4_s[lane >> 4][ch][rg * 64 + (lane & 1)];

        v2f wbuf[8][2];
        #pragma unroll
        for (int j = 0; j < 8; ++j) {
            float4 w4 = *reinterpret_cast<const float4*>(wp + j * HH);
            wbuf[j][0] = mk2(w4.x, w4.y); wbuf[j][1] = mk2(w4.z, w4.w);
        }

        float sEven = 0.f;
        #pragma unroll 1
        for (int hs8 = 0; hs8 < 64; hs8 += 8) {
            #pragma unroll
            for (int j = 0; j < 8; ++j) {
                const int row = hs8 + j;
                const float4* q = reinterpret_cast<const float4*>(bp + row * RANK);
                float4 q0 = q[0], q1 = q[1];
                v2f bz0 = mk2(q0.x, q0.y), bz1 = mk2(q0.z, q0.w);
                v2f bz2 = mk2(q1.x, q1.y), bz3 = mk2(q1.z, q1.w);

                v2f sv = mk2(0.f, 0.f);
                #pragma unroll
                for (int gg = 0; gg < 2; ++gg) {
                    v2f d = wbuf[j][gg];
                    d = pk_fma_blo(az[0][gg], bz0, d);
                    d = pk_fma_bhi(az[1][gg], bz0, d);
                    d = pk_fma_blo(az[2][gg], bz1, d);
                    d = pk_fma_bhi(az[3][gg], bz1, d);
                    d = pk_fma_blo(az[4][gg], bz2, d);
                    d = pk_fma_bhi(az[5][gg], bz2, d);
                    d = pk_fma_blo(az[6][gg], bz3, d);
                    d = pk_fma_bhi(az[7][gg], bz3, d);
                    v2f u = pk_mul(d, d);
                    v2f t = pk_fma(u, cA2, cB2);
                    t = pk_fma(u, t, cL2);
                    t = pk_fma(d, cH2, t);
                    sv = pk_fma(zk2[gg], t, sv);
                }
                float s = sv.x + sv.y;
                {
                    float4 w4 = *reinterpret_cast<const float4*>(wp + ((row + 8) & 63) * HH);
                    wbuf[j][0] = mk2(w4.x, w4.y); wbuf[j][1] = mk2(w4.z, w4.w);
                }
                if (j & 1) {
                    float m = odd ? s : sEven;
                    float o = odd ? sEven : s;
                    m = m + __int_as_float(__builtin_amdgcn_update_dpp(
                            0, __float_as_int(o), 0xB1, 0xf, 0xf, true));
                    DPP_ADD(m, 0x112, 0xf, 0xf, true);
                    DPP_ADD(m, 0x114, 0xf, 0xf, true);
                    DPP_ADD(m, 0x118, 0xf, 0xf, true);
                    if ((lane & 14) == 14) rp[row - 1] = m;
                } else {
                    sEven = s;
                }
            }
        }
    };

    zlayer(Wz1, 0);
    __syncthreads();
    if (tid < HH) {
        float acc = xpre_s[1][tid];
        #pragma unroll
        for (int q = 0; q < 4; ++q) acc += red4_s[q][0][tid] + red4_s[q][1][tid];
        z_s[tid] = sp_stable(acc);
    }
    __syncthreads();

    zlayer(Wz2, 1);
    __syncthreads();
    if (tid < HH) {
        float acc = xpre_s[2][tid];
        #pragma unroll
        for (int q = 0; q < 4; ++q) acc += red4_s[q][0][tid] + red4_s[q][1][tid];
        z_s[tid] = sp_stable(acc);
    }
    __syncthreads();

    {
        float partial = 0.f;
        if (tid < HH) {
            const float* oBzb = oBz + b * RANK;
            const float* oAzb = oAz + b * RANK * HH;
            float d = 0.f;
            #pragma unroll
            for (int r = 0; r < RANK; ++r) d = fmaf(oBzb[r], oAzb[r * HH + tid], d);
            partial = z_s[tid] * sp_poly(fmaf(SCALE, d, oWz[tid]));
            if (tid < DIN) partial += oWx[tid] * x_s[tid];
        }
        partial = wave_sum64(partial);
        if (lane == 63) red8[wid] = partial;
        __syncthreads();
        if (tid == 0) {
            float t = 0.f;
            #pragma unroll
            for (int w = 0; w < 8; ++w) t += red8[w];
            float t2 = 0.f;
            const float* oBxb = oBx + b * RANK;
            #pragma unroll
            for (int r = 0; r < RANK; ++r) t2 = fmaf(oBxb[r], tx_s[3][r], t2);
            out[b] = t + ob[0] + obd[b] + SCALE * t2;
        }
    }
}

extern "C" void kernel_launch(void* const* d_in, const int* in_sizes, int n_in,
                              void* d_out, int out_size, void* d_ws, size_t ws_size,
                              hipStream_t stream) {
    const float* x   = (const float*)d_in[0];
    const float* Wx0 = (const float*)d_in[1];
    const float* b0  = (const float*)d_in[2];
    const float* Ax0 = (const float*)d_in[3];
    const float* Bx0 = (const float*)d_in[4];
    const float* bd0 = (const float*)d_in[5];
    const float* Wx1 = (const float*)d_in[6];
    const float* b1  = (const float*)d_in[7];
    const float* Ax1 = (const float*)d_in[8];
    const float* Bx1 = (const float*)d_in[9];
    const float* bd1 = (const float*)d_in[10];
    const float* Wx2 = (const float*)d_in[11];
    const float* b2  = (const float*)d_in[12];
    const float* Ax2 = (const float*)d_in[13];
    const float* Bx2 = (const float*)d_in[14];
    const float* bd2 = (const float*)d_in[15];
    const float* Wz1 = (const float*)d_in[16];
    const float* Az1 = (const float*)d_in[17];
    const float* Bz1 = (const float*)d_in[18];
    const float* Wz2 = (const float*)d_in[19];
    const float* Az2 = (const float*)d_in[20];
    const float* Bz2 = (const float*)d_in[21];
    const float* oWx = (const float*)d_in[22];
    const float* ob  = (const float*)d_in[23];
    const float* oAx = (const float*)d_in[24];
    const float* oBx = (const float*)d_in[25];
    const float* obd = (const float*)d_in[26];
    const float* oWz = (const float*)d_in[27];
    const float* oAz = (const float*)d_in[28];
    const float* oBz = (const float*)d_in[29];
    float* out = (float*)d_out;

    if (ws_size >= (size_t)WS_END * sizeof(float) && d_ws != nullptr) {
        float* ws = (float*)d_ws;
        _Float16* W16 = (_Float16*)(ws + WS_W16);
        _Float16* B16 = (_Float16*)(ws + WS_B16);
        kprep<<<NB, 1024, 0, stream>>>(x, Wx0, b0, Ax0, Bx0, bd0,
                                       Wx1, b1, Ax1, Bx1, bd1,
                                       Wx2, b2, Ax2, Bx2, bd2,
                                       Az1, Wz1, Wz2, ws);
        kz<<<1408, 256, 0, stream>>>(W16, B16, ws + WS_ACC);
        kmid<<<NB, 1024, 0, stream>>>(Az2, Bz1, ws);
        kz<<<1408, 256, 0, stream>>>(W16 + 786432, B16 + (size_t)2304 * 512, ws + WS_ACC);
        kout<<<NB, 512, 0, stream>>>(x, oWx, ob, oAx, oBx, obd,
                                     oWz, oAz, oBz, Bz2, ws, out);
    } else {
        lora_fused<<<NB, 1024, 0, stream>>>(
            x, Wx0, b0, Ax0, Bx0, bd0, Wx1, b1, Ax1, Bx1, bd1,
            Wx2, b2, Ax2, Bx2, bd2, Wz1, Az1, Bz1, Wz2, Az2, Bz2,
            oWx, ob, oAx, oBx, obd, oWz, oAz, oBz, out);
    }
}

// Round 8
// 91.129 us; speedup vs baseline: 1.0476x; 1.0476x over previous
//
#include <hip/hip_runtime.h>

#define NB    256
#define DIN   128
#define HH    512
#define RANK  8
#define SCALE 2.0f
#define LN2   0.69314718f
#define C192  5.2083335e-3f

// ---- workspace layout (float offsets); poison fill of d_ws is OUTSIDE the
// timed window (established r5/r6: dur_us ~= our kernels' rocprof time only).
#define WS_Z0   0         // [256 s][512]  z0 (activated)
#define WS_XP1  131072    // [256 s][512]  xpre layer 1
#define WS_XP2  262144    // [256 s][512]  xpre layer 2
#define WS_P1   393216    // [256 s][512]  pre1
#define WS_P2   524288    // [256 s][512]  pre2
#define WS_END  655360

typedef float v2f __attribute__((ext_vector_type(2)));
typedef _Float16 h4v __attribute__((ext_vector_type(4)));

__device__ __forceinline__ v2f mk2(float a, float b) { v2f r; r.x = a; r.y = b; return r; }

// ---- packed fp32 VOP3P helpers (2 FMAs per instruction) ----
__device__ __forceinline__ v2f pk_fma(v2f a, v2f b, v2f c) {
    v2f d; asm("v_pk_fma_f32 %0, %1, %2, %3" : "=v"(d) : "v"(a), "v"(b), "v"(c)); return d;
}
__device__ __forceinline__ v2f pk_mul(v2f a, v2f b) {
    v2f d; asm("v_pk_mul_f32 %0, %1, %2" : "=v"(d) : "v"(a), "v"(b)); return d;
}
__device__ __forceinline__ v2f pk_fma_blo(v2f a, v2f b, v2f c) {
    v2f d; asm("v_pk_fma_f32 %0, %1, %2, %3 op_sel:[0,0,0] op_sel_hi:[1,0,1]"
               : "=v"(d) : "v"(a), "v"(b), "v"(c)); return d;
}
__device__ __forceinline__ v2f pk_fma_bhi(v2f a, v2f b, v2f c) {
    v2f d; asm("v_pk_fma_f32 %0, %1, %2, %3 op_sel:[0,1,0] op_sel_hi:[1,1,1]"
               : "=v"(d) : "v"(a), "v"(b), "v"(c)); return d;
}

__device__ __forceinline__ float sp_stable(float v) {
    float e = __expf(-fabsf(v));
    return fmaxf(v, 0.0f) + __logf(1.0f + e);
}
__device__ __forceinline__ float sp_poly(float v) {
    float u = v * v;
    float t = fmaf(u, -C192, 0.125f);
    t = fmaf(u, t, LN2);
    return fmaf(v, 0.5f, t);
}

#define DPP_ADD(x, ctrl, rm, bm, bc)                                            \
    (x) = (x) + __int_as_float(__builtin_amdgcn_update_dpp(                     \
              0, __float_as_int(x), (ctrl), (rm), (bm), (bc)))

__device__ __forceinline__ float wave_sum64(float x) {
    DPP_ADD(x, 0x111, 0xf, 0xf, true);
    DPP_ADD(x, 0x112, 0xf, 0xf, true);
    DPP_ADD(x, 0x114, 0xf, 0xf, true);
    DPP_ADD(x, 0x118, 0xf, 0xf, true);
    DPP_ADD(x, 0x142, 0xa, 0xf, false);
    DPP_ADD(x, 0x143, 0xc, 0xf, false);
    return x;
}

// ------------------------------------------------------------------
// kprep: all x-path work for all 3 layers. One block per sample.
// Writes z0 (activated), xpre1, xpre2 to ws.
// ------------------------------------------------------------------
__global__ __launch_bounds__(1024, 4) void kprep(
    const float* __restrict__ x,
    const float* __restrict__ Wx0, const float* __restrict__ b0,
    const float* __restrict__ Ax0, const float* __restrict__ Bx0, const float* __restrict__ bd0,
    const float* __restrict__ Wx1, const float* __restrict__ b1,
    const float* __restrict__ Ax1, const float* __restrict__ Bx1, const float* __restrict__ bd1,
    const float* __restrict__ Wx2, const float* __restrict__ b2,
    const float* __restrict__ Ax2, const float* __restrict__ Bx2, const float* __restrict__ bd2,
    float* __restrict__ ws)
{
    const int b = blockIdx.x, tid = threadIdx.x;
    __shared__ float x_s[DIN];
    __shared__ float tx_s[3][RANK];

    if (tid < DIN) x_s[tid] = x[b * DIN + tid];
    __syncthreads();

    if (tid < 384) {
        const int g = tid >> 7, t = tid & 127;
        const int r = t >> 4, l = t & 15;
        const float* A  = (g == 0) ? Ax0 : (g == 1) ? Ax1 : Ax2;
        const float* Ab = A + ((size_t)b * RANK + r) * DIN;
        float s = 0.f;
        #pragma unroll
        for (int k = 0; k < 8; ++k) { int d = l + 16 * k; s += Ab[d] * x_s[d]; }
        s += __shfl_down(s, 8, 16);
        s += __shfl_down(s, 4, 16);
        s += __shfl_down(s, 2, 16);
        s += __shfl_down(s, 1, 16);
        if (l == 0) tx_s[g][r] = s;
    }
    __syncthreads();

    #pragma unroll 1
    for (int idx = tid; idx < 3 * HH; idx += 1024) {
        const int l = idx >> 9;            // wave-uniform
        const int h = idx & (HH - 1);
        const float* Wxl = (l == 0) ? Wx0 : (l == 1) ? Wx1 : Wx2;
        const float* bl  = (l == 0) ? b0  : (l == 1) ? b1  : b2;
        const float* Bxl = (l == 0) ? Bx0 : (l == 1) ? Bx1 : Bx2;
        const float* bdl = (l == 0) ? bd0 : (l == 1) ? bd1 : bd2;
        const float4* wrow = reinterpret_cast<const float4*>(Wxl + h * DIN);
        float s = 0.f;
        #pragma unroll 8
        for (int q = 0; q < DIN / 4; ++q) {
            float4 w = wrow[q];
            const float* xs = &x_s[q * 4];
            s += w.x * xs[0] + w.y * xs[1] + w.z * xs[2] + w.w * xs[3];
        }
        const float* bxr = Bxl + ((size_t)b * HH + h) * RANK;
        float t = 0.f;
        #pragma unroll
        for (int r = 0; r < RANK; ++r) t += bxr[r] * tx_s[l][r];
        const float v = s + SCALE * t + bl[h] + bdl[(size_t)b * HH + h];
        if (l == 0)      ws[WS_Z0  + b * HH + h] = sp_stable(v);
        else if (l == 1) ws[WS_XP1 + b * HH + h] = v;
        else             ws[WS_XP2 + b * HH + h] = v;
    }
}

// ------------------------------------------------------------------
// kzstep: z-GEMV only. block = (sample-pair p, 64-row group g).
// grid 1024 = 128 pairs x 8 groups; 512 threads (8 waves: s x khalf x rhalf);
// LDS ~76 KB -> TWO independent blocks per CU (the round-8 lever).
// mode 1: out = xpre + sum_k z_k * sp_poly(...)   (zin already activated)
// mode 2: same but zin = pre1, activated at staging.
// ------------------------------------------------------------------
__global__ __launch_bounds__(512, 4) void kzstep(
    const float* __restrict__ Wz, const float* __restrict__ Az,
    const float* __restrict__ Bz,
    const float* __restrict__ zin, const float* __restrict__ xpre,
    float* __restrict__ outv, const int mode)
{
    const int bid  = blockIdx.x;
    const int p    = bid >> 3;       // sample pair 0..127
    const int g    = bid & 7;        // row group 0..7 (64 rows)
    const int tid  = threadIdx.x;
    const int lane = tid & 63;
    const int wid  = tid >> 6;       // 0..7

    __shared__ _Float16 Wt[64 * HH];             // fp16 Wz tile (64 KB)
    __shared__ float z_s[2][HH];                 // 4 KB
    __shared__ float bz_s[2][64][RANK];          // 4 KB
    __shared__ float red_s[4][2][2][66];         // [quad][s][khalf][row] 4.2 KB

    const v2f cA2 = mk2(-C192, -C192);
    const v2f cB2 = mk2(0.125f, 0.125f);
    const v2f cL2 = mk2(LN2, LN2);
    const v2f cH2 = mk2(0.5f, 0.5f);

    // ---- stage Wz rows -> fp16 tile ----
    #pragma unroll
    for (int j = 0; j < 16; ++j) {
        const int fi  = tid + j * 512;           // 0..8191 h4v slots
        const int row = fi >> 7, c4 = fi & 127;
        float4 w = *reinterpret_cast<const float4*>(Wz + (size_t)(g * 64 + row) * HH + c4 * 4);
        h4v hv;
        hv.x = (_Float16)w.x; hv.y = (_Float16)w.y;
        hv.z = (_Float16)w.z; hv.w = (_Float16)w.w;
        reinterpret_cast<h4v*>(Wt)[fi] = hv;
    }
    // ---- stage z (2 samples) and bz (2 samples x 64 rows) ----
    if (tid < 256) {
        const int s = tid >> 7, k4 = tid & 127;
        float4 zv = *reinterpret_cast<const float4*>(zin + (size_t)(p * 2 + s) * HH + k4 * 4);
        if (mode == 2) {
            zv.x = sp_stable(zv.x); zv.y = sp_stable(zv.y);
            zv.z = sp_stable(zv.z); zv.w = sp_stable(zv.w);
        }
        *reinterpret_cast<float4*>(&z_s[s][k4 * 4]) = zv;
    } else {
        const int t = tid - 256;
        const int s = t >> 7, t2 = t & 127;
        const int rw = t2 >> 1, q = t2 & 1;
        *reinterpret_cast<float4*>(&bz_s[s][rw][q * 4]) =
            *reinterpret_cast<const float4*>(
                Bz + ((size_t)(p * 2 + s) * HH + g * 64 + rw) * RANK + q * 4);
    }
    __syncthreads();

    // ---- z-GEMV: wave (s, khalf, rhalf) -> 32 rows x 256 cols ----
    {
        const int s   = wid & 1;
        const int khf = (wid >> 1) & 1;
        const int rh  = wid >> 2;
        const int c0  = khf * 256 + (lane << 2);
        const int sb  = p * 2 + s;
        const bool odd = lane & 1;

        v2f zk2[2], az[RANK][2];
        {
            float4 zz = *reinterpret_cast<const float4*>(&z_s[s][c0]);
            zk2[0] = mk2(zz.x, zz.y); zk2[1] = mk2(zz.z, zz.w);
        }
        #pragma unroll
        for (int r = 0; r < RANK; ++r) {
            float4 a4 = *reinterpret_cast<const float4*>(Az + ((size_t)sb * RANK + r) * HH + c0);
            az[r][0] = mk2(SCALE * a4.x, SCALE * a4.y);
            az[r][1] = mk2(SCALE * a4.z, SCALE * a4.w);
        }

        const _Float16* wp = Wt + (size_t)(rh * 32) * HH + c0;
        const float* bp = &bz_s[s][rh * 32][0];
        float* rp = &red_s[lane >> 4][s][khf][rh * 32 + (lane & 1)];

        v2f wA[2], wB[2], bzA[4], bzB[4];

        auto loadw = [&](v2f* dst, int row) {
            h4v hv = *reinterpret_cast<const h4v*>(wp + row * HH);
            dst[0] = mk2((float)hv.x, (float)hv.y);
            dst[1] = mk2((float)hv.z, (float)hv.w);
        };
        auto loadb = [&](v2f* dst, int row) {
            float4 q0 = *reinterpret_cast<const float4*>(bp + row * RANK);
            float4 q1 = *reinterpret_cast<const float4*>(bp + row * RANK + 4);
            dst[0] = mk2(q0.x, q0.y); dst[1] = mk2(q0.z, q0.w);
            dst[2] = mk2(q1.x, q1.y); dst[3] = mk2(q1.z, q1.w);
        };
        auto rowsum = [&](const v2f* wz, const v2f* bz) -> float {
            v2f sv = mk2(0.f, 0.f);
            #pragma unroll
            for (int gg = 0; gg < 2; ++gg) {
                v2f d = wz[gg];
                d = pk_fma_blo(az[0][gg], bz[0], d);
                d = pk_fma_bhi(az[1][gg], bz[0], d);
                d = pk_fma_blo(az[2][gg], bz[1], d);
                d = pk_fma_bhi(az[3][gg], bz[1], d);
                d = pk_fma_blo(az[4][gg], bz[2], d);
                d = pk_fma_bhi(az[5][gg], bz[2], d);
                d = pk_fma_blo(az[6][gg], bz[3], d);
                d = pk_fma_bhi(az[7][gg], bz[3], d);
                v2f u = pk_mul(d, d);
                v2f t = pk_fma(u, cA2, cB2);
                t = pk_fma(u, t, cL2);
                t = pk_fma(d, cH2, t);
                sv = pk_fma(zk2[gg], t, sv);
            }
            return sv.x + sv.y;
        };

        loadw(wA, 0); loadb(bzA, 0);
        #pragma unroll 1
        for (int hs = 0; hs < 32; hs += 2) {
            loadw(wB, hs + 1); loadb(bzB, hs + 1);
            float sA = rowsum(wA, bzA);
            const int hn = (hs + 2) & 31;   // wrap keeps in-bounds; wrapped row unused
            loadw(wA, hn); loadb(bzA, hn);
            float sB = rowsum(wB, bzB);

            float m  = odd ? sB : sA;
            float o2 = odd ? sA : sB;
            m = m + __int_as_float(__builtin_amdgcn_update_dpp(
                    0, __float_as_int(o2), 0xB1, 0xf, 0xf, true)); // quad_perm xor1
            DPP_ADD(m, 0x112, 0xf, 0xf, true);
            DPP_ADD(m, 0x114, 0xf, 0xf, true);
            DPP_ADD(m, 0x118, 0xf, 0xf, true);
            if ((lane & 14) == 14) rp[hs] = m;
        }
    }
    __syncthreads();

    // ---- combine partials + xpre -> out ----
    if (tid < 128) {
        const int row = tid >> 1, s = tid & 1;
        const int sb = p * 2 + s, h = g * 64 + row;
        float acc = xpre[(size_t)sb * HH + h];
        #pragma unroll
        for (int q = 0; q < 4; ++q)
            acc += red_s[q][s][0][row] + red_s[q][s][1][row];
        outv[(size_t)sb * HH + h] = acc;
    }
}

// ------------------------------------------------------------------
// kout: z2 = sp(pre2); output layer; reduce to out[b].
// ------------------------------------------------------------------
__global__ __launch_bounds__(512, 2) void kout(
    const float* __restrict__ x,
    const float* __restrict__ oWx, const float* __restrict__ ob,
    const float* __restrict__ oAx, const float* __restrict__ oBx, const float* __restrict__ obd,
    const float* __restrict__ oWz, const float* __restrict__ oAz, const float* __restrict__ oBz,
    const float* __restrict__ pre2, float* __restrict__ out)
{
    const int b = blockIdx.x, tid = threadIdx.x;
    __shared__ float x_s[DIN];
    __shared__ float red_s[HH];
    __shared__ float tx_s[RANK];

    if (tid < DIN) x_s[tid] = x[b * DIN + tid];
    __syncthreads();

    float partial;
    {
        const int h = tid;
        const float z2 = sp_stable(pre2[(size_t)b * HH + h]);
        float d = 0.f;
        #pragma unroll
        for (int r = 0; r < RANK; ++r)
            d = fmaf(oBz[b * RANK + r], oAz[((size_t)b * RANK + r) * HH + h], d);
        partial = z2 * sp_poly(fmaf(SCALE, d, oWz[h]));
        if (tid < DIN) partial += oWx[tid] * x_s[tid];
    }
    red_s[tid] = partial;
    __syncthreads();

    if (tid < 128) {
        const int r = tid >> 4, l = tid & 15;
        const float* Ab = oAx + ((size_t)b * RANK + r) * DIN;
        float s = 0.f;
        #pragma unroll
        for (int k = 0; k < 8; ++k) { int d = l + 16 * k; s += Ab[d] * x_s[d]; }
        s += __shfl_down(s, 8, 16);
        s += __shfl_down(s, 4, 16);
        s += __shfl_down(s, 2, 16);
        s += __shfl_down(s, 1, 16);
        if (l == 0) tx_s[r] = s;
    }
    __syncthreads();
    for (int st = 256; st > 0; st >>= 1) {
        if (tid < st) red_s[tid] += red_s[tid + st];
        __syncthreads();
    }
    if (tid == 0) {
        float t2 = 0.f;
        #pragma unroll
        for (int r = 0; r < RANK; ++r) t2 = fmaf(oBx[b * RANK + r], tx_s[r], t2);
        out[b] = red_s[0] + ob[0] + obd[b] + SCALE * t2;
    }
}

// ==================================================================
// Fallback single-kernel path (round-5 kernel, 76.3 us) if ws too small.
// ==================================================================
__global__ __launch_bounds__(1024, 4) void lora_fused(
    const float* __restrict__ x,
    const float* __restrict__ Wx0, const float* __restrict__ b0,
    const float* __restrict__ Ax0, const float* __restrict__ Bx0, const float* __restrict__ bd0,
    const float* __restrict__ Wx1, const float* __restrict__ b1,
    const float* __restrict__ Ax1, const float* __restrict__ Bx1, const float* __restrict__ bd1,
    const float* __restrict__ Wx2, const float* __restrict__ b2,
    const float* __restrict__ Ax2, const float* __restrict__ Bx2, const float* __restrict__ bd2,
    const float* __restrict__ Wz1, const float* __restrict__ Az1, const float* __restrict__ Bz1,
    const float* __restrict__ Wz2, const float* __restrict__ Az2, const float* __restrict__ Bz2,
    const float* __restrict__ oWx, const float* __restrict__ ob,
    const float* __restrict__ oAx, const float* __restrict__ oBx, const float* __restrict__ obd,
    const float* __restrict__ oWz, const float* __restrict__ oAz, const float* __restrict__ oBz,
    float* __restrict__ out)
{
    const int b    = blockIdx.x;
    const int tid  = threadIdx.x;
    const int lane = tid & 63;
    const int wid  = tid >> 6;
    const int rg   = wid >> 1;
    const int ch   = wid & 1;
    const bool odd = lane & 1;

    __shared__ float x_s[DIN];
    __shared__ float z_s[HH];
    __shared__ float tx_s[4][RANK];
    __shared__ float xpre_s[3][HH];
    __shared__ float red4_s[4][2][HH + 2];
    __shared__ __attribute__((aligned(16))) float Az_s[2][RANK * HH];
    __shared__ __attribute__((aligned(16))) float Bz_s[2][HH * RANK];
    __shared__ float red8[16];

    const v2f cA2 = mk2(-C192, -C192);
    const v2f cB2 = mk2(0.125f, 0.125f);
    const v2f cL2 = mk2(LN2, LN2);
    const v2f cH2 = mk2(0.5f, 0.5f);

    if (tid < DIN) x_s[tid] = x[b * DIN + tid];
    {
        const float4* a1 = reinterpret_cast<const float4*>(Az1 + b * RANK * HH);
        const float4* a2 = reinterpret_cast<const float4*>(Az2 + b * RANK * HH);
        const float4* z1 = reinterpret_cast<const float4*>(Bz1 + b * HH * RANK);
        const float4* z2 = reinterpret_cast<const float4*>(Bz2 + b * HH * RANK);
        reinterpret_cast<float4*>(Az_s[0])[tid] = a1[tid];
        reinterpret_cast<float4*>(Az_s[1])[tid] = a2[tid];
        reinterpret_cast<float4*>(Bz_s[0])[tid] = z1[tid];
        reinterpret_cast<float4*>(Bz_s[1])[tid] = z2[tid];
    }
    __syncthreads();

    if (tid < 512) {
        const int g = tid >> 7;
        const int t = tid & 127;
        const int r = t >> 4, l = t & 15;
        const float* A  = (g == 0) ? Ax0 : (g == 1) ? Ax1 : (g == 2) ? Ax2 : oAx;
        const float* Ab = A + (b * RANK + r) * DIN;
        float s = 0.f;
        #pragma unroll
        for (int k = 0; k < 8; ++k) { int d = l + 16 * k; s += Ab[d] * x_s[d]; }
        s += __shfl_down(s, 8, 16);
        s += __shfl_down(s, 4, 16);
        s += __shfl_down(s, 2, 16);
        s += __shfl_down(s, 1, 16);
        if (l == 0) tx_s[g][r] = s;
    }
    __syncthreads();

    #pragma unroll 1
    for (int idx = tid; idx < 3 * HH; idx += 1024) {
        const int l = idx >> 9;
        const int h = idx & (HH - 1);
        const float* Wxl = (l == 0) ? Wx0 : (l == 1) ? Wx1 : Wx2;
        const float* bl  = (l == 0) ? b0  : (l == 1) ? b1  : b2;
        const float* Bxl = (l == 0) ? Bx0 : (l == 1) ? Bx1 : Bx2;
        const float* bdl = (l == 0) ? bd0 : (l == 1) ? bd1 : bd2;
        const float4* wrow = reinterpret_cast<const float4*>(Wxl + h * DIN);
        float s = 0.f;
        #pragma unroll 8
        for (int q = 0; q < DIN / 4; ++q) {
            float4 w = wrow[q];
            const float* xs = &x_s[q * 4];
            s += w.x * xs[0] + w.y * xs[1] + w.z * xs[2] + w.w * xs[3];
        }
        const float* bxr = Bxl + (b * HH + h) * RANK;
        float t = 0.f;
        #pragma unroll
        for (int r = 0; r < RANK; ++r) t += bxr[r] * tx_s[l][r];
        xpre_s[l][h] = s + SCALE * t + bl[h] + bdl[b * HH + h];
    }
    __syncthreads();

    if (tid < HH) z_s[tid] = sp_stable(xpre_s[0][tid]);
    __syncthreads();

    auto zlayer = [&](const float* __restrict__ Wz, int li) {
        const int c0 = ch * 256 + (lane << 2);
        v2f zk2[2], az[RANK][2];
        {
            float4 zz = *reinterpret_cast<const float4*>(&z_s[c0]);
            zk2[0] = mk2(zz.x, zz.y); zk2[1] = mk2(zz.z, zz.w);
        }
        #pragma unroll
        for (int r = 0; r < RANK; ++r) {
            float4 a4 = *reinterpret_cast<const float4*>(&Az_s[li][r * HH + c0]);
            az[r][0] = mk2(SCALE * a4.x, SCALE * a4.y);
            az[r][1] = mk2(SCALE * a4.z, SCALE * a4.w);
        }
        const float* wp = Wz + (rg * 64) * HH + c0;
        const float* bp = &Bz_s[li][(rg * 64) * RANK];
        float* rp = &red4_s[lane >> 4][ch][rg * 64 + (lane & 1)];

        v2f wbuf[8][2];
        #pragma unroll
        for (int j = 0; j < 8; ++j) {
            float4 w4 = *reinterpret_cast<const float4*>(wp + j * HH);
            wbuf[j][0] = mk2(w4.x, w4.y); wbuf[j][1] = mk2(w4.z, w4.w);
        }

        float sEven = 0.f;
        #pragma unroll 1
        for (int hs8 = 0; hs8 < 64; hs8 += 8) {
            #pragma unroll
            for (int j = 0; j < 8; ++j) {
                const int row = hs8 + j;
                const float4* q = reinterpret_cast<const float4*>(bp + row * RANK);
                float4 q0 = q[0], q1 = q[1];
                v2f bz0 = mk2(q0.x, q0.y), bz1 = mk2(q0.z, q0.w);
                v2f bz2 = mk2(q1.x, q1.y), bz3 = mk2(q1.z, q1.w);

                v2f sv = mk2(0.f, 0.f);
                #pragma unroll
                for (int gg = 0; gg < 2; ++gg) {
                    v2f d = wbuf[j][gg];
                    d = pk_fma_blo(az[0][gg], bz0, d);
                    d = pk_fma_bhi(az[1][gg], bz0, d);
                    d = pk_fma_blo(az[2][gg], bz1, d);
                    d = pk_fma_bhi(az[3][gg], bz1, d);
                    d = pk_fma_blo(az[4][gg], bz2, d);
                    d = pk_fma_bhi(az[5][gg], bz2, d);
                    d = pk_fma_blo(az[6][gg], bz3, d);
                    d = pk_fma_bhi(az[7][gg], bz3, d);
                    v2f u = pk_mul(d, d);
                    v2f t = pk_fma(u, cA2, cB2);
                    t = pk_fma(u, t, cL2);
                    t = pk_fma(d, cH2, t);
                    sv = pk_fma(zk2[gg], t, sv);
                }
                float s = sv.x + sv.y;
                {
                    float4 w4 = *reinterpret_cast<const float4*>(wp + ((row + 8) & 63) * HH);
                    wbuf[j][0] = mk2(w4.x, w4.y); wbuf[j][1] = mk2(w4.z, w4.w);
                }
                if (j & 1) {
                    float m = odd ? s : sEven;
                    float o = odd ? sEven : s;
                    m = m + __int_as_float(__builtin_amdgcn_update_dpp(
                            0, __float_as_int(o), 0xB1, 0xf, 0xf, true));
                    DPP_ADD(m, 0x112, 0xf, 0xf, true);
                    DPP_ADD(m, 0x114, 0xf, 0xf, true);
                    DPP_ADD(m, 0x118, 0xf, 0xf, true);
                    if ((lane & 14) == 14) rp[row - 1] = m;
                } else {
                    sEven = s;
                }
            }
        }
    };

    zlayer(Wz1, 0);
    __syncthreads();
    if (tid < HH) {
        float acc = xpre_s[1][tid];
        #pragma unroll
        for (int q = 0; q < 4; ++q) acc += red4_s[q][0][tid] + red4_s[q][1][tid];
        z_s[tid] = sp_stable(acc);
    }
    __syncthreads();

    zlayer(Wz2, 1);
    __syncthreads();
    if (tid < HH) {
        float acc = xpre_s[2][tid];
        #pragma unroll
        for (int q = 0; q < 4; ++q) acc += red4_s[q][0][tid] + red4_s[q][1][tid];
        z_s[tid] = sp_stable(acc);
    }
    __syncthreads();

    {
        float partial = 0.f;
        if (tid < HH) {
            const float* oBzb = oBz + b * RANK;
            const float* oAzb = oAz + b * RANK * HH;
            float d = 0.f;
            #pragma unroll
            for (int r = 0; r < RANK; ++r) d = fmaf(oBzb[r], oAzb[r * HH + tid], d);
            partial = z_s[tid] * sp_poly(fmaf(SCALE, d, oWz[tid]));
            if (tid < DIN) partial += oWx[tid] * x_s[tid];
        }
        partial = wave_sum64(partial);
        if (lane == 63) red8[wid] = partial;
        __syncthreads();
        if (tid == 0) {
            float t = 0.f;
            #pragma unroll
            for (int w = 0; w < 8; ++w) t += red8[w];
            float t2 = 0.f;
            const float* oBxb = oBx + b * RANK;
            #pragma unroll
            for (int r = 0; r < RANK; ++r) t2 = fmaf(oBxb[r], tx_s[3][r], t2);
            out[b] = t + ob[0] + obd[b] + SCALE * t2;
        }
    }
}

extern "C" void kernel_launch(void* const* d_in, const int* in_sizes, int n_in,
                              void* d_out, int out_size, void* d_ws, size_t ws_size,
                              hipStream_t stream) {
    const float* x   = (const float*)d_in[0];
    const float* Wx0 = (const float*)d_in[1];
    const float* b0  = (const float*)d_in[2];
    const float* Ax0 = (const float*)d_in[3];
    const float* Bx0 = (const float*)d_in[4];
    const float* bd0 = (const float*)d_in[5];
    const float* Wx1 = (const float*)d_in[6];
    const float* b1  = (const float*)d_in[7];
    const float* Ax1 = (const float*)d_in[8];
    const float* Bx1 = (const float*)d_in[9];
    const float* bd1 = (const float*)d_in[10];
    const float* Wx2 = (const float*)d_in[11];
    const float* b2  = (const float*)d_in[12];
    const float* Ax2 = (const float*)d_in[13];
    const float* Bx2 = (const float*)d_in[14];
    const float* bd2 = (const float*)d_in[15];
    const float* Wz1 = (const float*)d_in[16];
    const float* Az1 = (const float*)d_in[17];
    const float* Bz1 = (const float*)d_in[18];
    const float* Wz2 = (const float*)d_in[19];
    const float* Az2 = (const float*)d_in[20];
    const float* Bz2 = (const float*)d_in[21];
    const float* oWx = (const float*)d_in[22];
    const float* ob  = (const float*)d_in[23];
    const float* oAx = (const float*)d_in[24];
    const float* oBx = (const float*)d_in[25];
    const float* obd = (const float*)d_in[26];
    const float* oWz = (const float*)d_in[27];
    const float* oAz = (const float*)d_in[28];
    const float* oBz = (const float*)d_in[29];
    float* out = (float*)d_out;

    if (ws_size >= (size_t)WS_END * sizeof(float) && d_ws != nullptr) {
        float* ws = (float*)d_ws;
        kprep<<<NB, 1024, 0, stream>>>(x, Wx0, b0, Ax0, Bx0, bd0,
                                       Wx1, b1, Ax1, Bx1, bd1,
                                       Wx2, b2, Ax2, Bx2, bd2, ws);
        kzstep<<<1024, 512, 0, stream>>>(Wz1, Az1, Bz1,
                                         ws + WS_Z0, ws + WS_XP1, ws + WS_P1, 1);
        kzstep<<<1024, 512, 0, stream>>>(Wz2, Az2, Bz2,
                                         ws + WS_P1, ws + WS_XP2, ws + WS_P2, 2);
        kout<<<NB, 512, 0, stream>>>(x, oWx, ob, oAx, oBx, obd,
                                     oWz, oAz, oBz, ws + WS_P2, out);
    } else {
        lora_fused<<<NB, 1024, 0, stream>>>(
            x, Wx0, b0, Ax0, Bx0, bd0, Wx1, b1, Ax1, Bx1, bd1,
            Wx2, b2, Ax2, Bx2, bd2, Wz1, Az1, Bz1, Wz2, Az2, Bz2,
            oWx, ob, oAx, oBx, obd, oWz, oAz, oBz, out);
    }
}

// Round 9
// 80.690 us; speedup vs baseline: 1.1831x; 1.1294x over previous
//
#include <hip/hip_runtime.h>

#define NB    256
#define DIN   128
#define HH    512
#define RANK  8
#define SCALE 2.0f
#define LN2   0.69314718f
#define C192  5.2083335e-3f

typedef float v2f __attribute__((ext_vector_type(2)));

__device__ __forceinline__ v2f mk2(float a, float b) { v2f r; r.x = a; r.y = b; return r; }

// ---- packed fp32 VOP3P helpers (2 FMAs per instruction) ----
__device__ __forceinline__ v2f pk_fma(v2f a, v2f b, v2f c) {
    v2f d; asm("v_pk_fma_f32 %0, %1, %2, %3" : "=v"(d) : "v"(a), "v"(b), "v"(c)); return d;
}
__device__ __forceinline__ v2f pk_mul(v2f a, v2f b) {
    v2f d; asm("v_pk_mul_f32 %0, %1, %2" : "=v"(d) : "v"(a), "v"(b)); return d;
}
__device__ __forceinline__ v2f pk_fma_blo(v2f a, v2f b, v2f c) {
    v2f d; asm("v_pk_fma_f32 %0, %1, %2, %3 op_sel:[0,0,0] op_sel_hi:[1,0,1]"
               : "=v"(d) : "v"(a), "v"(b), "v"(c)); return d;
}
__device__ __forceinline__ v2f pk_fma_bhi(v2f a, v2f b, v2f c) {
    v2f d; asm("v_pk_fma_f32 %0, %1, %2, %3 op_sel:[0,1,0] op_sel_hi:[1,1,1]"
               : "=v"(d) : "v"(a), "v"(b), "v"(c)); return d;
}

__device__ __forceinline__ float sp_stable(float v) {
    float e = __expf(-fabsf(v));
    return fmaxf(v, 0.0f) + __logf(1.0f + e);
}
__device__ __forceinline__ float sp_poly(float v) {
    float u = v * v;
    float t = fmaf(u, -C192, 0.125f);
    t = fmaf(u, t, LN2);
    return fmaf(v, 0.5f, t);
}

#define DPP_ADD(x, ctrl, rm, bm, bc)                                            \
    (x) = (x) + __int_as_float(__builtin_amdgcn_update_dpp(                     \
              0, __float_as_int(x), (ctrl), (rm), (bm), (bc)))

__device__ __forceinline__ float wave_sum64(float x) {
    DPP_ADD(x, 0x111, 0xf, 0xf, true);
    DPP_ADD(x, 0x112, 0xf, 0xf, true);
    DPP_ADD(x, 0x114, 0xf, 0xf, true);
    DPP_ADD(x, 0x118, 0xf, 0xf, true);
    DPP_ADD(x, 0x142, 0xa, 0xf, false);
    DPP_ADD(x, 0x143, 0xc, 0xf, false);
    return x;
}

__global__ __launch_bounds__(1024, 4) void lora_fused(
    const float* __restrict__ x,
    const float* __restrict__ Wx0, const float* __restrict__ b0,
    const float* __restrict__ Ax0, const float* __restrict__ Bx0, const float* __restrict__ bd0,
    const float* __restrict__ Wx1, const float* __restrict__ b1,
    const float* __restrict__ Ax1, const float* __restrict__ Bx1, const float* __restrict__ bd1,
    const float* __restrict__ Wx2, const float* __restrict__ b2,
    const float* __restrict__ Ax2, const float* __restrict__ Bx2, const float* __restrict__ bd2,
    const float* __restrict__ Wz1, const float* __restrict__ Az1, const float* __restrict__ Bz1,
    const float* __restrict__ Wz2, const float* __restrict__ Az2, const float* __restrict__ Bz2,
    const float* __restrict__ oWx, const float* __restrict__ ob,
    const float* __restrict__ oAx, const float* __restrict__ oBx, const float* __restrict__ obd,
    const float* __restrict__ oWz, const float* __restrict__ oAz, const float* __restrict__ oBz,
    float* __restrict__ out)
{
    const int b    = blockIdx.x;
    const int tid  = threadIdx.x;
    const int lane = tid & 63;
    const int wid  = tid >> 6;     // 0..15
    const int rg   = wid >> 1;     // row group   0..7 (64 rows each)
    const int ch   = wid & 1;      // column half 0..1 (256 cols each)
    const bool odd = lane & 1;

    // LDS total ~158.5 KB (fits 160 KB): ALL cold per-sample inputs staged.
    __shared__ float x_s[DIN];
    __shared__ float z_s[HH];
    __shared__ float tx_s[4][RANK];
    __shared__ float xpre_s[3][HH];
    __shared__ float red4_s[4][2][HH + 2];
    __shared__ __attribute__((aligned(16))) float Az_s[2][RANK * HH];
    __shared__ __attribute__((aligned(16))) float Bz_s[2][HH * RANK];
    __shared__ float Bx_s[3][HH][9];                 // padded row: no bank conflict
    __shared__ __attribute__((aligned(16))) float Ax_s[3][RANK * DIN];
    __shared__ float red8[16];

    const v2f cA2 = mk2(-C192, -C192);
    const v2f cB2 = mk2(0.125f, 0.125f);
    const v2f cL2 = mk2(LN2, LN2);
    const v2f cH2 = mk2(0.5f, 0.5f);

    // ---- PHASE A: single front-loaded burst of ALL cold per-sample bytes ----
    // 9 independent float4 loads issued into register temps BEFORE any LDS
    // store waits -> ~128 KB in flight per CU (vs ~8 KB demand-paged before).
    {
        const float4* gAz1 = reinterpret_cast<const float4*>(Az1 + (size_t)b * RANK * HH);
        const float4* gAz2 = reinterpret_cast<const float4*>(Az2 + (size_t)b * RANK * HH);
        const float4* gBz1 = reinterpret_cast<const float4*>(Bz1 + (size_t)b * HH * RANK);
        const float4* gBz2 = reinterpret_cast<const float4*>(Bz2 + (size_t)b * HH * RANK);
        const float4* gBx0 = reinterpret_cast<const float4*>(Bx0 + (size_t)b * HH * RANK);
        const float4* gBx1 = reinterpret_cast<const float4*>(Bx1 + (size_t)b * HH * RANK);
        const float4* gBx2 = reinterpret_cast<const float4*>(Bx2 + (size_t)b * HH * RANK);

        float4 tA1 = gAz1[tid], tA2 = gAz2[tid];
        float4 tB1 = gBz1[tid], tB2 = gBz2[tid];
        float4 tX0 = gBx0[tid], tX1 = gBx1[tid], tX2 = gBx2[tid];
        float4 tAx, tx4;
        if (tid < 768) {
            const float* Axl = (tid < 256) ? Ax0 : (tid < 512) ? Ax1 : Ax2;
            tAx = reinterpret_cast<const float4*>(Axl + (size_t)b * RANK * DIN)[tid & 255];
        }
        if (tid < 32) tx4 = reinterpret_cast<const float4*>(x + b * DIN)[tid];

        reinterpret_cast<float4*>(Az_s[0])[tid] = tA1;
        reinterpret_cast<float4*>(Az_s[1])[tid] = tA2;
        reinterpret_cast<float4*>(Bz_s[0])[tid] = tB1;
        reinterpret_cast<float4*>(Bz_s[1])[tid] = tB2;
        {   // Bx rows padded to 9 floats -> scalar stores (36 B stride)
            const int row = tid >> 1, c4 = (tid & 1) * 4;
            float* p0 = &Bx_s[0][row][c4];
            p0[0] = tX0.x; p0[1] = tX0.y; p0[2] = tX0.z; p0[3] = tX0.w;
            float* p1 = &Bx_s[1][row][c4];
            p1[0] = tX1.x; p1[1] = tX1.y; p1[2] = tX1.z; p1[3] = tX1.w;
            float* p2 = &Bx_s[2][row][c4];
            p2[0] = tX2.x; p2[1] = tX2.y; p2[2] = tX2.z; p2[3] = tX2.w;
        }
        if (tid < 768) reinterpret_cast<float4*>(&Ax_s[0][0])[tid] = tAx;
        if (tid < 32)  reinterpret_cast<float4*>(x_s)[tid] = tx4;
    }
    __syncthreads();

    // ---- tx for all 4 layers: tx_s[g][r] = sum_d A_g[b,r,d]*x[d] (Ax from LDS)
    if (tid < 512) {
        const int g = tid >> 7;            // layer: 0,1,2,3(out) — wave-uniform
        const int t = tid & 127;
        const int r = t >> 4, l = t & 15;
        const float* Ab = (g < 3) ? &Ax_s[g][r * DIN]
                                  : (oAx + ((size_t)b * RANK + r) * DIN);
        float s = 0.f;
        #pragma unroll
        for (int k = 0; k < 8; ++k) { int d = l + 16 * k; s += Ab[d] * x_s[d]; }
        s += __shfl_down(s, 8, 16);
        s += __shfl_down(s, 4, 16);
        s += __shfl_down(s, 2, 16);
        s += __shfl_down(s, 1, 16);
        if (l == 0) tx_s[g][r] = s;
    }
    __syncthreads();

    // ---- all 3 layers' x-path pre-activations (Bx from LDS; Wx from L2) ----
    #pragma unroll 1
    for (int idx = tid; idx < 3 * HH; idx += 1024) {
        const int l = idx >> 9;            // wave-uniform
        const int h = idx & (HH - 1);
        const float* Wxl = (l == 0) ? Wx0 : (l == 1) ? Wx1 : Wx2;
        const float* bl  = (l == 0) ? b0  : (l == 1) ? b1  : b2;
        const float* bdl = (l == 0) ? bd0 : (l == 1) ? bd1 : bd2;
        const float4* wrow = reinterpret_cast<const float4*>(Wxl + h * DIN);
        const float bdv = bdl[(size_t)b * HH + h];   // issue early
        float s = 0.f;
        #pragma unroll 8
        for (int q = 0; q < DIN / 4; ++q) {
            float4 w = wrow[q];
            const float* xs = &x_s[q * 4];
            s += w.x * xs[0] + w.y * xs[1] + w.z * xs[2] + w.w * xs[3];
        }
        const float* bxr = &Bx_s[l][h][0];
        float t = 0.f;
        #pragma unroll
        for (int r = 0; r < RANK; ++r) t += bxr[r] * tx_s[l][r];
        xpre_s[l][h] = s + SCALE * t + bl[h] + bdv;
    }
    __syncthreads();

    // ---- layer 0 ----
    if (tid < HH) z_s[tid] = sp_stable(xpre_s[0][tid]);
    __syncthreads();

    // Wave-cooperative z-path: wave owns 64 rows x 256 cols (4 cols/lane).
    // Wz stream: 8-deep register pipeline (validated round 5).
    auto zlayer = [&](const float* __restrict__ Wz, int li) {
        const int c0 = ch * 256 + (lane << 2);
        v2f zk2[2], az[RANK][2];
        {
            float4 zz = *reinterpret_cast<const float4*>(&z_s[c0]);
            zk2[0] = mk2(zz.x, zz.y); zk2[1] = mk2(zz.z, zz.w);
        }
        #pragma unroll
        for (int r = 0; r < RANK; ++r) {
            float4 a4 = *reinterpret_cast<const float4*>(&Az_s[li][r * HH + c0]);
            az[r][0] = mk2(SCALE * a4.x, SCALE * a4.y);
            az[r][1] = mk2(SCALE * a4.z, SCALE * a4.w);
        }

        const float* wp = Wz + (rg * 64) * HH + c0;
        const float* bp = &Bz_s[li][(rg * 64) * RANK];
        float* rp = &red4_s[lane >> 4][ch][rg * 64 + (lane & 1)];

        v2f wbuf[8][2];
        #pragma unroll
        for (int j = 0; j < 8; ++j) {
            float4 w4 = *reinterpret_cast<const float4*>(wp + j * HH);
            wbuf[j][0] = mk2(w4.x, w4.y); wbuf[j][1] = mk2(w4.z, w4.w);
        }

        float sEven = 0.f;
        #pragma unroll 1
        for (int hs8 = 0; hs8 < 64; hs8 += 8) {
            #pragma unroll
            for (int j = 0; j < 8; ++j) {
                const int row = hs8 + j;
                const float4* q = reinterpret_cast<const float4*>(bp + row * RANK);
                float4 q0 = q[0], q1 = q[1];
                v2f bz0 = mk2(q0.x, q0.y), bz1 = mk2(q0.z, q0.w);
                v2f bz2 = mk2(q1.x, q1.y), bz3 = mk2(q1.z, q1.w);

                v2f sv = mk2(0.f, 0.f);
                #pragma unroll
                for (int gg = 0; gg < 2; ++gg) {
                    v2f d = wbuf[j][gg];
                    d = pk_fma_blo(az[0][gg], bz0, d);
                    d = pk_fma_bhi(az[1][gg], bz0, d);
                    d = pk_fma_blo(az[2][gg], bz1, d);
                    d = pk_fma_bhi(az[3][gg], bz1, d);
                    d = pk_fma_blo(az[4][gg], bz2, d);
                    d = pk_fma_bhi(az[5][gg], bz2, d);
                    d = pk_fma_blo(az[6][gg], bz3, d);
                    d = pk_fma_bhi(az[7][gg], bz3, d);
                    v2f u = pk_mul(d, d);
                    v2f t = pk_fma(u, cA2, cB2);
                    t = pk_fma(u, t, cL2);
                    t = pk_fma(d, cH2, t);
                    sv = pk_fma(zk2[gg], t, sv);
                }
                float s = sv.x + sv.y;
                {   // refill slot j with row+8 (wrap keeps in-bounds)
                    float4 w4 = *reinterpret_cast<const float4*>(wp + ((row + 8) & 63) * HH);
                    wbuf[j][0] = mk2(w4.x, w4.y); wbuf[j][1] = mk2(w4.z, w4.w);
                }
                if (j & 1) {
                    float m = odd ? s : sEven;
                    float o = odd ? sEven : s;
                    m = m + __int_as_float(__builtin_amdgcn_update_dpp(
                            0, __float_as_int(o), 0xB1, 0xf, 0xf, true));
                    DPP_ADD(m, 0x112, 0xf, 0xf, true);
                    DPP_ADD(m, 0x114, 0xf, 0xf, true);
                    DPP_ADD(m, 0x118, 0xf, 0xf, true);
                    if ((lane & 14) == 14) rp[row - 1] = m;
                } else {
                    sEven = s;
                }
            }
        }
    };

    // ---- layer 1 ----
    zlayer(Wz1, 0);
    __syncthreads();
    if (tid < HH) {
        float acc = xpre_s[1][tid];
        #pragma unroll
        for (int q = 0; q < 4; ++q) acc += red4_s[q][0][tid] + red4_s[q][1][tid];
        z_s[tid] = sp_stable(acc);
    }
    __syncthreads();

    // ---- layer 2 ----
    zlayer(Wz2, 1);
    __syncthreads();
    if (tid < HH) {
        float acc = xpre_s[2][tid];
        #pragma unroll
        for (int q = 0; q < 4; ++q) acc += red4_s[q][0][tid] + red4_s[q][1][tid];
        z_s[tid] = sp_stable(acc);
    }
    __syncthreads();

    // ---- output layer ----
    {
        float partial = 0.f;
        if (tid < HH) {
            const float* oBzb = oBz + b * RANK;
            const float* oAzb = oAz + (size_t)b * RANK * HH;
            float d = 0.f;
            #pragma unroll
            for (int r = 0; r < RANK; ++r) d = fmaf(oBzb[r], oAzb[r * HH + tid], d);
            partial = z_s[tid] * sp_poly(fmaf(SCALE, d, oWz[tid]));
            if (tid < DIN) partial += oWx[tid] * x_s[tid];
        }
        partial = wave_sum64(partial);
        if (lane == 63) red8[wid] = partial;
        __syncthreads();
        if (tid == 0) {
            float t = 0.f;
            #pragma unroll
            for (int w = 0; w < 8; ++w) t += red8[w];
            float t2 = 0.f;
            const float* oBxb = oBx + b * RANK;
            #pragma unroll
            for (int r = 0; r < RANK; ++r) t2 = fmaf(oBxb[r], tx_s[3][r], t2);
            out[b] = t + ob[0] + obd[b] + SCALE * t2;
        }
    }
}

extern "C" void kernel_launch(void* const* d_in, const int* in_sizes, int n_in,
                              void* d_out, int out_size, void* d_ws, size_t ws_size,
                              hipStream_t stream) {
    const float* x   = (const float*)d_in[0];
    const float* Wx0 = (const float*)d_in[1];
    const float* b0  = (const float*)d_in[2];
    const float* Ax0 = (const float*)d_in[3];
    const float* Bx0 = (const float*)d_in[4];
    const float* bd0 = (const float*)d_in[5];
    const float* Wx1 = (const float*)d_in[6];
    const float* b1  = (const float*)d_in[7];
    const float* Ax1 = (const float*)d_in[8];
    const float* Bx1 = (const float*)d_in[9];
    const float* bd1 = (const float*)d_in[10];
    const float* Wx2 = (const float*)d_in[11];
    const float* b2  = (const float*)d_in[12];
    const float* Ax2 = (const float*)d_in[13];
    const float* Bx2 = (const float*)d_in[14];
    const float* bd2 = (const float*)d_in[15];
    const float* Wz1 = (const float*)d_in[16];
    const float* Az1 = (const float*)d_in[17];
    const float* Bz1 = (const float*)d_in[18];
    const float* Wz2 = (const float*)d_in[19];
    const float* Az2 = (const float*)d_in[20];
    const float* Bz2 = (const float*)d_in[21];
    const float* oWx = (const float*)d_in[22];
    const float* ob  = (const float*)d_in[23];
    const float* oAx = (const float*)d_in[24];
    const float* oBx = (const float*)d_in[25];
    const float* obd = (const float*)d_in[26];
    const float* oWz = (const float*)d_in[27];
    const float* oAz = (const float*)d_in[28];
    const float* oBz = (const float*)d_in[29];
    float* out = (float*)d_out;

    lora_fused<<<NB, 1024, 0, stream>>>(
        x, Wx0, b0, Ax0, Bx0, bd0, Wx1, b1, Ax1, Bx1, bd1,
        Wx2, b2, Ax2, Bx2, bd2, Wz1, Az1, Bz1, Wz2, Az2, Bz2,
        oWx, ob, oAx, oBx, obd, oWz, oAz, oBz, out);
}

// Round 10
// 76.290 us; speedup vs baseline: 1.2514x; 1.0577x over previous
//
#include <hip/hip_runtime.h>

#define NB    256
#define DIN   128
#define HH    512
#define RANK  8
#define SCALE 2.0f
#define LN2   0.69314718f
#define C192  5.2083335e-3f

typedef float v2f __attribute__((ext_vector_type(2)));

__device__ __forceinline__ v2f mk2(float a, float b) { v2f r; r.x = a; r.y = b; return r; }

// ---- packed fp32 VOP3P helpers (2 FMAs per instruction) ----
__device__ __forceinline__ v2f pk_fma(v2f a, v2f b, v2f c) {
    v2f d; asm("v_pk_fma_f32 %0, %1, %2, %3" : "=v"(d) : "v"(a), "v"(b), "v"(c)); return d;
}
__device__ __forceinline__ v2f pk_mul(v2f a, v2f b) {
    v2f d; asm("v_pk_mul_f32 %0, %1, %2" : "=v"(d) : "v"(a), "v"(b)); return d;
}
// broadcast b.lo to both halves
__device__ __forceinline__ v2f pk_fma_blo(v2f a, v2f b, v2f c) {
    v2f d; asm("v_pk_fma_f32 %0, %1, %2, %3 op_sel:[0,0,0] op_sel_hi:[1,0,1]"
               : "=v"(d) : "v"(a), "v"(b), "v"(c)); return d;
}
// broadcast b.hi to both halves
__device__ __forceinline__ v2f pk_fma_bhi(v2f a, v2f b, v2f c) {
    v2f d; asm("v_pk_fma_f32 %0, %1, %2, %3 op_sel:[0,1,0] op_sel_hi:[1,1,1]"
               : "=v"(d) : "v"(a), "v"(b), "v"(c)); return d;
}

__device__ __forceinline__ float sp_stable(float v) {
    float e = __expf(-fabsf(v));
    return fmaxf(v, 0.0f) + __logf(1.0f + e);
}
__device__ __forceinline__ float sp_poly(float v) {
    float u = v * v;
    float t = fmaf(u, -C192, 0.125f);
    t = fmaf(u, t, LN2);
    return fmaf(v, 0.5f, t);
}

#define DPP_ADD(x, ctrl, rm, bm, bc)                                            \
    (x) = (x) + __int_as_float(__builtin_amdgcn_update_dpp(                     \
              0, __float_as_int(x), (ctrl), (rm), (bm), (bc)))

__device__ __forceinline__ float wave_sum64(float x) {
    DPP_ADD(x, 0x111, 0xf, 0xf, true);
    DPP_ADD(x, 0x112, 0xf, 0xf, true);
    DPP_ADD(x, 0x114, 0xf, 0xf, true);
    DPP_ADD(x, 0x118, 0xf, 0xf, true);
    DPP_ADD(x, 0x142, 0xa, 0xf, false);
    DPP_ADD(x, 0x143, 0xc, 0xf, false);
    return x;
}

__global__ __launch_bounds__(1024, 4) void lora_fused(
    const float* __restrict__ x,
    const float* __restrict__ Wx0, const float* __restrict__ b0,
    const float* __restrict__ Ax0, const float* __restrict__ Bx0, const float* __restrict__ bd0,
    const float* __restrict__ Wx1, const float* __restrict__ b1,
    const float* __restrict__ Ax1, const float* __restrict__ Bx1, const float* __restrict__ bd1,
    const float* __restrict__ Wx2, const float* __restrict__ b2,
    const float* __restrict__ Ax2, const float* __restrict__ Bx2, const float* __restrict__ bd2,
    const float* __restrict__ Wz1, const float* __restrict__ Az1, const float* __restrict__ Bz1,
    const float* __restrict__ Wz2, const float* __restrict__ Az2, const float* __restrict__ Bz2,
    const float* __restrict__ oWx, const float* __restrict__ ob,
    const float* __restrict__ oAx, const float* __restrict__ oBx, const float* __restrict__ obd,
    const float* __restrict__ oWz, const float* __restrict__ oAz, const float* __restrict__ oBz,
    float* __restrict__ out)
{
    const int b    = blockIdx.x;
    const int tid  = threadIdx.x;
    const int lane = tid & 63;
    const int wid  = tid >> 6;     // 0..15
    const int rg   = wid >> 1;     // row group   0..7 (64 rows each)
    const int ch   = wid & 1;      // column half 0..1 (256 cols each)
    const bool odd = lane & 1;

    __shared__ float x_s[DIN];
    __shared__ float z_s[HH];
    __shared__ float tx_s[4][RANK];            // per-layer Ax@x (0,1,2,out)
    __shared__ float xpre_s[3][HH];            // hoisted x-path pre-activations
    __shared__ float red4_s[4][2][HH + 2];     // [16-lane-quadrant][col-half][row]
    __shared__ __attribute__((aligned(16))) float Az_s[2][RANK * HH];
    __shared__ __attribute__((aligned(16))) float Bz_s[2][HH * RANK];
    __shared__ float red8[16];

    // packed sp_poly constants
    const v2f cA2 = mk2(-C192, -C192);
    const v2f cB2 = mk2(0.125f, 0.125f);
    const v2f cL2 = mk2(LN2, LN2);
    const v2f cH2 = mk2(0.5f, 0.5f);

    // ---- prologue: stage x + all per-sample z-LoRA factors into LDS ----
    if (tid < DIN) x_s[tid] = x[b * DIN + tid];
    {
        const float4* a1 = reinterpret_cast<const float4*>(Az1 + b * RANK * HH);
        const float4* a2 = reinterpret_cast<const float4*>(Az2 + b * RANK * HH);
        const float4* z1 = reinterpret_cast<const float4*>(Bz1 + b * HH * RANK);
        const float4* z2 = reinterpret_cast<const float4*>(Bz2 + b * HH * RANK);
        reinterpret_cast<float4*>(Az_s[0])[tid] = a1[tid];
        reinterpret_cast<float4*>(Az_s[1])[tid] = a2[tid];
        reinterpret_cast<float4*>(Bz_s[0])[tid] = z1[tid];
        reinterpret_cast<float4*>(Bz_s[1])[tid] = z2[tid];
    }
    __syncthreads();

    // ---- tx for all 4 layers in parallel: tx_s[g][r] = sum_d A_g[b,r,d]*x[d]
    if (tid < 512) {
        const int g = tid >> 7;            // layer: 0,1,2,3(out) — wave-uniform
        const int t = tid & 127;
        const int r = t >> 4, l = t & 15;
        const float* A  = (g == 0) ? Ax0 : (g == 1) ? Ax1 : (g == 2) ? Ax2 : oAx;
        const float* Ab = A + (b * RANK + r) * DIN;
        float s = 0.f;
        #pragma unroll
        for (int k = 0; k < 8; ++k) { int d = l + 16 * k; s += Ab[d] * x_s[d]; }
        s += __shfl_down(s, 8, 16);
        s += __shfl_down(s, 4, 16);
        s += __shfl_down(s, 2, 16);
        s += __shfl_down(s, 1, 16);
        if (l == 0) tx_s[g][r] = s;
    }
    __syncthreads();

    // ---- all 3 layers' x-path pre-activations, fully parallel (1536 rows) ----
    #pragma unroll 1
    for (int idx = tid; idx < 3 * HH; idx += 1024) {
        const int l = idx >> 9;            // wave-uniform (512-row chunks)
        const int h = idx & (HH - 1);
        const float* Wxl = (l == 0) ? Wx0 : (l == 1) ? Wx1 : Wx2;
        const float* bl  = (l == 0) ? b0  : (l == 1) ? b1  : b2;
        const float* Bxl = (l == 0) ? Bx0 : (l == 1) ? Bx1 : Bx2;
        const float* bdl = (l == 0) ? bd0 : (l == 1) ? bd1 : bd2;
        const float4* wrow = reinterpret_cast<const float4*>(Wxl + h * DIN);
        float s = 0.f;
        #pragma unroll 8
        for (int q = 0; q < DIN / 4; ++q) {
            float4 w = wrow[q];
            const float* xs = &x_s[q * 4];
            s += w.x * xs[0] + w.y * xs[1] + w.z * xs[2] + w.w * xs[3];
        }
        const float* bxr = Bxl + (b * HH + h) * RANK;
        float t = 0.f;
        #pragma unroll
        for (int r = 0; r < RANK; ++r) t += bxr[r] * tx_s[l][r];
        xpre_s[l][h] = s + SCALE * t + bl[h] + bdl[b * HH + h];
    }
    __syncthreads();

    // ---- layer 0 ----
    if (tid < HH) z_s[tid] = sp_stable(xpre_s[0][tid]);
    __syncthreads();

    // Wave-cooperative z-path: wave owns 64 rows x 256 cols (4 consecutive cols/lane).
    // Wz stream: 8-deep register pipeline (8 dwordx4 in flight per wave) to cover
    // L2/HBM latency; statically-indexed circular buffer via 8x-unrolled inner loop.
    auto zlayer = [&](const float* __restrict__ Wz, int li) {
        const int c0 = ch * 256 + (lane << 2);
        v2f zk2[2], az[RANK][2];
        {
            float4 zz = *reinterpret_cast<const float4*>(&z_s[c0]);
            zk2[0] = mk2(zz.x, zz.y); zk2[1] = mk2(zz.z, zz.w);
        }
        #pragma unroll
        for (int r = 0; r < RANK; ++r) {
            float4 a4 = *reinterpret_cast<const float4*>(&Az_s[li][r * HH + c0]);
            az[r][0] = mk2(SCALE * a4.x, SCALE * a4.y);
            az[r][1] = mk2(SCALE * a4.z, SCALE * a4.w);
        }

        const float* wp = Wz + (rg * 64) * HH + c0;
        const float* bp = &Bz_s[li][(rg * 64) * RANK];
        float* rp = &red4_s[lane >> 4][ch][rg * 64 + (lane & 1)];

        // prologue: fill 8-row register pipeline
        v2f wbuf[8][2];
        #pragma unroll
        for (int j = 0; j < 8; ++j) {
            float4 w4 = *reinterpret_cast<const float4*>(wp + j * HH);
            wbuf[j][0] = mk2(w4.x, w4.y); wbuf[j][1] = mk2(w4.z, w4.w);
        }

        float sEven = 0.f;
        #pragma unroll 1
        for (int hs8 = 0; hs8 < 64; hs8 += 8) {
            #pragma unroll
            for (int j = 0; j < 8; ++j) {
                const int row = hs8 + j;
                // bz from LDS (uniform address -> broadcast)
                const float4* q = reinterpret_cast<const float4*>(bp + row * RANK);
                float4 q0 = q[0], q1 = q[1];
                v2f bz0 = mk2(q0.x, q0.y), bz1 = mk2(q0.z, q0.w);
                v2f bz2 = mk2(q1.x, q1.y), bz3 = mk2(q1.z, q1.w);

                v2f sv = mk2(0.f, 0.f);
                #pragma unroll
                for (int gg = 0; gg < 2; ++gg) {
                    v2f d = wbuf[j][gg];
                    d = pk_fma_blo(az[0][gg], bz0, d);
                    d = pk_fma_bhi(az[1][gg], bz0, d);
                    d = pk_fma_blo(az[2][gg], bz1, d);
                    d = pk_fma_bhi(az[3][gg], bz1, d);
                    d = pk_fma_blo(az[4][gg], bz2, d);
                    d = pk_fma_bhi(az[5][gg], bz2, d);
                    d = pk_fma_blo(az[6][gg], bz3, d);
                    d = pk_fma_bhi(az[7][gg], bz3, d);
                    v2f u = pk_mul(d, d);
                    v2f t = pk_fma(u, cA2, cB2);
                    t = pk_fma(u, t, cL2);
                    t = pk_fma(d, cH2, t);      // sp_poly(d), packed
                    sv = pk_fma(zk2[gg], t, sv);
                }
                float s = sv.x + sv.y;

                // refill slot j with row+8 (wrap keeps in-bounds; wrapped rows unused)
                {
                    float4 w4 = *reinterpret_cast<const float4*>(wp + ((row + 8) & 63) * HH);
                    wbuf[j][0] = mk2(w4.x, w4.y); wbuf[j][1] = mk2(w4.z, w4.w);
                }

                if (j & 1) {
                    // merged 2-row reduce: even row on even lanes, odd row on odd lanes
                    float m = odd ? s : sEven;
                    float o = odd ? sEven : s;
                    m = m + __int_as_float(__builtin_amdgcn_update_dpp(
                            0, __float_as_int(o), 0xB1, 0xf, 0xf, true)); // quad_perm xor1
                    DPP_ADD(m, 0x112, 0xf, 0xf, true);   // row_shr:2 (parity-preserving)
                    DPP_ADD(m, 0x114, 0xf, 0xf, true);   // row_shr:4
                    DPP_ADD(m, 0x118, 0xf, 0xf, true);   // row_shr:8
                    if ((lane & 14) == 14) rp[row - 1] = m;
                } else {
                    sEven = s;
                }
            }
        }
    };

    // ---- layer 1 ----
    zlayer(Wz1, 0);
    __syncthreads();
    if (tid < HH) {
        float acc = xpre_s[1][tid];
        #pragma unroll
        for (int q = 0; q < 4; ++q) acc += red4_s[q][0][tid] + red4_s[q][1][tid];
        z_s[tid] = sp_stable(acc);
    }
    __syncthreads();

    // ---- layer 2 ----
    zlayer(Wz2, 1);
    __syncthreads();
    if (tid < HH) {
        float acc = xpre_s[2][tid];
        #pragma unroll
        for (int q = 0; q < 4; ++q) acc += red4_s[q][0][tid] + red4_s[q][1][tid];
        z_s[tid] = sp_stable(acc);
    }
    __syncthreads();

    // ---- output layer ----
    {
        float partial = 0.f;
        if (tid < HH) {
            const float* oBzb = oBz + b * RANK;
            const float* oAzb = oAz + b * RANK * HH;
            float d = 0.f;
            #pragma unroll
            for (int r = 0; r < RANK; ++r) d = fmaf(oBzb[r], oAzb[r * HH + tid], d);
            partial = z_s[tid] * sp_poly(fmaf(SCALE, d, oWz[tid]));
            if (tid < DIN) partial += oWx[tid] * x_s[tid];
        }
        partial = wave_sum64(partial);
        if (lane == 63) red8[wid] = partial;
        __syncthreads();
        if (tid == 0) {
            float t = 0.f;
            #pragma unroll
            for (int w = 0; w < 8; ++w) t += red8[w];
            float t2 = 0.f;
            const float* oBxb = oBx + b * RANK;
            #pragma unroll
            for (int r = 0; r < RANK; ++r) t2 = fmaf(oBxb[r], tx_s[3][r], t2);
            out[b] = t + ob[0] + obd[b] + SCALE * t2;
        }
    }
}

extern "C" void kernel_launch(void* const* d_in, const int* in_sizes, int n_in,
                              void* d_out, int out_size, void* d_ws, size_t ws_size,
                              hipStream_t stream) {
    const float* x   = (const float*)d_in[0];
    const float* Wx0 = (const float*)d_in[1];
    const float* b0  = (const float*)d_in[2];
    const float* Ax0 = (const float*)d_in[3];
    const float* Bx0 = (const float*)d_in[4];
    const float* bd0 = (const float*)d_in[5];
    const float* Wx1 = (const float*)d_in[6];
    const float* b1  = (const float*)d_in[7];
    const float* Ax1 = (const float*)d_in[8];
    const float* Bx1 = (const float*)d_in[9];
    const float* bd1 = (const float*)d_in[10];
    const float* Wx2 = (const float*)d_in[11];
    const float* b2  = (const float*)d_in[12];
    const float* Ax2 = (const float*)d_in[13];
    const float* Bx2 = (const float*)d_in[14];
    const float* bd2 = (const float*)d_in[15];
    const float* Wz1 = (const float*)d_in[16];
    const float* Az1 = (const float*)d_in[17];
    const float* Bz1 = (const float*)d_in[18];
    const float* Wz2 = (const float*)d_in[19];
    const float* Az2 = (const float*)d_in[20];
    const float* Bz2 = (const float*)d_in[21];
    const float* oWx = (const float*)d_in[22];
    const float* ob  = (const float*)d_in[23];
    const float* oAx = (const float*)d_in[24];
    const float* oBx = (const float*)d_in[25];
    const float* obd = (const float*)d_in[26];
    const float* oWz = (const float*)d_in[27];
    const float* oAz = (const float*)d_in[28];
    const float* oBz = (const float*)d_in[29];
    float* out = (float*)d_out;

    lora_fused<<<NB, 1024, 0, stream>>>(
        x, Wx0, b0, Ax0, Bx0, bd0, Wx1, b1, Ax1, Bx1, bd1,
        Wx2, b2, Ax2, Bx2, bd2, Wz1, Az1, Bz1, Wz2, Az2, Bz2,
        oWx, ob, oAx, oBx, obd, oWz, oAz, oBz, out);
}